// Round 1
// baseline (3862.942 us; speedup 1.0000x reference)
//
#include <hip/hip_runtime.h>
#include <hip/hip_bf16.h>
#include <math.h>

// MLA forward, fp32 correctness-first pipeline.
// Workspace usage: ~93 MB (assumed available in d_ws).
// Stage graph:
//   gemm: c_kv = h@w_dkv^T, c_q = h@w_dq^T, krt = h@w_kr^T
//   batched gemm: kb[:, :,0:128]=c_kv@w_uk^T  vb=c_kv@w_uv^T
//                 qb[:, :,0:128]=c_q@w_uq^T   qb[:, :,128:192]=c_q@w_qr^T
//   rope_q (in place), rope_k (+1/16 scale, broadcast to 16 heads)
//   row_stats: softmax max/denom per (n,t) over causal l<=t
//   attn_pv: out2[l, e*16+n] = sum_t P[t,l] * v[t,e]   (transposed PV per reference)
//   gemm: d_out = out2 @ w_o^T

namespace {

constexpr int T   = 2048;
constexpr int D   = 2048;
constexpr int NH  = 16;
constexpr int DH  = 128;
constexpr int DRH = 64;
constexpr int DC  = 512;
constexpr int QK  = DH + DRH; // 192
constexpr float SCALE = 0.07216878364870322f; // 1/sqrt(192)

// C[M,N] = A[M,K] @ B[N,K]^T ; grid = (M/BM, N/BN, batch); 256 threads.
// All dims must divide tiles exactly (true for every call site here).
template<int BM, int BN, int TM, int TN>
__global__ __launch_bounds__(256) void gemm_nt(
    const float* __restrict__ A, const float* __restrict__ B, float* __restrict__ C,
    int K, int lda, int ldb, int ldc,
    long long sA, long long sB, long long sC)
{
    constexpr int BK = 16;
    constexpr int TX = BN / TN;
    __shared__ float As[BM][BK + 1];
    __shared__ float Bs[BN][BK + 1];
    const int tid = (int)threadIdx.x;
    const int tx = tid % TX;
    const int ty = tid / TX;
    const int z = (int)blockIdx.z;
    const float* Ab = A + (long long)z * sA;
    const float* Bb = B + (long long)z * sB;
    float* Cb = C + (long long)z * sC;
    const int row0 = (int)blockIdx.x * BM;
    const int col0 = (int)blockIdx.y * BN;

    float acc[TM][TN];
#pragma unroll
    for (int i = 0; i < TM; ++i)
#pragma unroll
        for (int j = 0; j < TN; ++j) acc[i][j] = 0.f;

    for (int k0 = 0; k0 < K; k0 += BK) {
#pragma unroll
        for (int it = 0; it < (BM * BK) / 1024; ++it) {
            int slot = tid + it * 256;
            int r = slot >> 2;
            int c = (slot & 3) * 4;
            const float4 v = *(const float4*)(Ab + (long long)(row0 + r) * lda + k0 + c);
            As[r][c] = v.x; As[r][c + 1] = v.y; As[r][c + 2] = v.z; As[r][c + 3] = v.w;
        }
#pragma unroll
        for (int it = 0; it < (BN * BK) / 1024; ++it) {
            int slot = tid + it * 256;
            int r = slot >> 2;
            int c = (slot & 3) * 4;
            const float4 v = *(const float4*)(Bb + (long long)(col0 + r) * ldb + k0 + c);
            Bs[r][c] = v.x; Bs[r][c + 1] = v.y; Bs[r][c + 2] = v.z; Bs[r][c + 3] = v.w;
        }
        __syncthreads();
#pragma unroll
        for (int kk = 0; kk < BK; ++kk) {
            float a[TM], b[TN];
#pragma unroll
            for (int i = 0; i < TM; ++i) a[i] = As[ty * TM + i][kk];
#pragma unroll
            for (int j = 0; j < TN; ++j) b[j] = Bs[tx * TN + j][kk];
#pragma unroll
            for (int i = 0; i < TM; ++i)
#pragma unroll
                for (int j = 0; j < TN; ++j) acc[i][j] += a[i] * b[j];
        }
        __syncthreads();
    }
#pragma unroll
    for (int i = 0; i < TM; ++i) {
        long long rowoff = (long long)(row0 + ty * TM + i) * ldc + col0 + tx * TN;
#pragma unroll
        for (int j = 0; j < TN; ++j) Cb[rowoff + j] = acc[i][j];
    }
}

// RoPE on q_r slice of qb[NH][T][192], columns 128..191, in place.
// pair (j, j+32): real' = x0*cos - x1*sin ; imag' = x0*sin + x1*cos
__global__ __launch_bounds__(256) void rope_q(float* __restrict__ qb,
                                              const float* __restrict__ fr)
{
    int idx = (int)blockIdx.x * 256 + (int)threadIdx.x; // NH*T*32
    int j = idx & 31;
    int t = (idx >> 5) & (T - 1);
    int n = idx >> 16;
    float ang = fr[t * 32 + j];
    float sn, cs;
    sincosf(ang, &sn, &cs);
    long long base = ((long long)(n * T + t)) * QK + DH + j;
    float x0 = qb[base];
    float x1 = qb[base + 32];
    qb[base]      = x0 * cs - x1 * sn;
    qb[base + 32] = x0 * sn + x1 * cs;
}

// RoPE k_r, scale by 1/NH, broadcast into all heads of kb[NH][T][192] cols 128..191.
__global__ __launch_bounds__(256) void rope_k(const float* __restrict__ krt,
                                              float* __restrict__ kb,
                                              const float* __restrict__ fr)
{
    int idx = (int)blockIdx.x * 256 + (int)threadIdx.x; // T*32
    int j = idx & 31;
    int t = idx >> 5;
    float ang = fr[t * 32 + j];
    float sn, cs;
    sincosf(ang, &sn, &cs);
    float x0 = krt[t * DRH + j];
    float x1 = krt[t * DRH + 32 + j];
    float y0 = (x0 * cs - x1 * sn) * (1.0f / 16.0f);
    float y1 = (x0 * sn + x1 * cs) * (1.0f / 16.0f);
#pragma unroll
    for (int n = 0; n < NH; ++n) {
        long long base = ((long long)(n * T + t)) * QK + DH + j;
        kb[base]      = y0;
        kb[base + 32] = y1;
    }
}

// Pass A: per (n,t) softmax stats over causal l<=t.
// grid (T/32, NH), 256 threads; 32x32 S tiles, 2x2 per thread.
__global__ __launch_bounds__(256) void row_stats(const float* __restrict__ qbuf,
                                                 const float* __restrict__ kbuf,
                                                 float* __restrict__ mrow,
                                                 float* __restrict__ zrow)
{
    int n = (int)blockIdx.y;
    int t0 = (int)blockIdx.x * 32;
    __shared__ float qs[32][193];
    __shared__ float ks[32][193];
    __shared__ float ms[32][17];
    __shared__ float zs[32][17];
    int tid = (int)threadIdx.x;
    int tx = tid & 15, ty = tid >> 4;

    const float* qbp = qbuf + ((long long)(n * T + t0)) * QK;
    for (int s = tid; s < 32 * 48; s += 256) {
        int r = s / 48, c = (s % 48) * 4;
        float4 v = *(const float4*)(qbp + r * QK + c);
        qs[r][c] = v.x; qs[r][c + 1] = v.y; qs[r][c + 2] = v.z; qs[r][c + 3] = v.w;
    }

    const int tA = ty * 2, tB = tA + 1, lA = tx * 2, lB = lA + 1;
    float m0 = -1e30f, m1 = -1e30f, z0 = 0.f, z1 = 0.f;
    const float* kbp = kbuf + (long long)n * T * QK;

    for (int l0 = 0; l0 <= t0; l0 += 32) {
        __syncthreads();
        for (int s = tid; s < 32 * 48; s += 256) {
            int r = s / 48, c = (s % 48) * 4;
            float4 v = *(const float4*)(kbp + (long long)(l0 + r) * QK + c);
            ks[r][c] = v.x; ks[r][c + 1] = v.y; ks[r][c + 2] = v.z; ks[r][c + 3] = v.w;
        }
        __syncthreads();
        float s00 = 0, s01 = 0, s10 = 0, s11 = 0;
        for (int kk = 0; kk < QK; ++kk) {
            float a0 = qs[tA][kk], a1 = qs[tB][kk];
            float b0 = ks[lA][kk], b1 = ks[lB][kk];
            s00 += a0 * b0; s01 += a0 * b1;
            s10 += a1 * b0; s11 += a1 * b1;
        }
        bool diag = (l0 == t0);
        {
            float s = s00 * SCALE;
            if (!diag || lA <= tA) { if (s > m0) { z0 = z0 * __expf(m0 - s) + 1.f; m0 = s; } else z0 += __expf(s - m0); }
        }
        {
            float s = s01 * SCALE;
            if (!diag || lB <= tA) { if (s > m0) { z0 = z0 * __expf(m0 - s) + 1.f; m0 = s; } else z0 += __expf(s - m0); }
        }
        {
            float s = s10 * SCALE;
            if (!diag || lA <= tB) { if (s > m1) { z1 = z1 * __expf(m1 - s) + 1.f; m1 = s; } else z1 += __expf(s - m1); }
        }
        {
            float s = s11 * SCALE;
            if (!diag || lB <= tB) { if (s > m1) { z1 = z1 * __expf(m1 - s) + 1.f; m1 = s; } else z1 += __expf(s - m1); }
        }
    }
    ms[tA][tx] = m0; zs[tA][tx] = z0;
    ms[tB][tx] = m1; zs[tB][tx] = z1;
    __syncthreads();
    if (tid < 32) {
        float m = -1e30f, z = 0.f;
        for (int i = 0; i < 16; ++i) {
            float mi = ms[tid][i], zi = zs[tid][i];
            float mm = fmaxf(m, mi);
            z = z * __expf(m - mm) + zi * __expf(mi - mm);
            m = mm;
        }
        mrow[n * T + t0 + tid] = m;
        zrow[n * T + t0 + tid] = 1.0f / z;
    }
}

// Pass B: out2[l, e*16+n] = sum_{t>=l} P[t,l] * v[t,e]
// grid (T/32 l-tiles, NH), 256 threads. Thread owns l'={ty*2,ty*2+1}, e=j*16+tx.
__global__ __launch_bounds__(256) void attn_pv(const float* __restrict__ qbuf,
                                               const float* __restrict__ kbuf,
                                               const float* __restrict__ vbuf,
                                               const float* __restrict__ mrow,
                                               const float* __restrict__ zrow,
                                               float* __restrict__ out2)
{
    int n = (int)blockIdx.y;
    int l0 = (int)blockIdx.x * 32;
    __shared__ float ks[32][193];
    __shared__ float qs[32][193];
    __shared__ float vs[32][129];
    __shared__ float Ps[32][33];
    __shared__ float mzm[32];
    __shared__ float mzz[32];
    int tid = (int)threadIdx.x;
    int tx = tid & 15, ty = tid >> 4;

    const float* kbp = kbuf + ((long long)(n * T + l0)) * QK;
    for (int s = tid; s < 32 * 48; s += 256) {
        int r = s / 48, c = (s % 48) * 4;
        float4 v = *(const float4*)(kbp + r * QK + c);
        ks[r][c] = v.x; ks[r][c + 1] = v.y; ks[r][c + 2] = v.z; ks[r][c + 3] = v.w;
    }

    float acc[2][8];
#pragma unroll
    for (int i = 0; i < 2; ++i)
#pragma unroll
        for (int j = 0; j < 8; ++j) acc[i][j] = 0.f;

    const int tA = ty * 2, tB = tA + 1, lA = tx * 2, lB = lA + 1;

    for (int t0 = l0; t0 < T; t0 += 32) {
        __syncthreads();
        const float* qbp = qbuf + ((long long)(n * T + t0)) * QK;
        for (int s = tid; s < 32 * 48; s += 256) {
            int r = s / 48, c = (s % 48) * 4;
            float4 v = *(const float4*)(qbp + r * QK + c);
            qs[r][c] = v.x; qs[r][c + 1] = v.y; qs[r][c + 2] = v.z; qs[r][c + 3] = v.w;
        }
        const float* vbp = vbuf + ((long long)(n * T + t0)) * DH;
        for (int s = tid; s < 32 * 32; s += 256) {
            int r = s / 32, c = (s % 32) * 4;
            float4 v = *(const float4*)(vbp + r * DH + c);
            vs[r][c] = v.x; vs[r][c + 1] = v.y; vs[r][c + 2] = v.z; vs[r][c + 3] = v.w;
        }
        if (tid < 32) {
            mzm[tid] = mrow[n * T + t0 + tid];
            mzz[tid] = zrow[n * T + t0 + tid];
        }
        __syncthreads();

        float s00 = 0, s01 = 0, s10 = 0, s11 = 0;
        for (int kk = 0; kk < QK; ++kk) {
            float a0 = qs[tA][kk], a1 = qs[tB][kk];
            float b0 = ks[lA][kk], b1 = ks[lB][kk];
            s00 += a0 * b0; s01 += a0 * b1;
            s10 += a1 * b0; s11 += a1 * b1;
        }
        bool diag = (t0 == l0);
        float p;
        p = (!diag || lA <= tA) ? __expf(s00 * SCALE - mzm[tA]) * mzz[tA] : 0.f; Ps[tA][lA] = p;
        p = (!diag || lB <= tA) ? __expf(s01 * SCALE - mzm[tA]) * mzz[tA] : 0.f; Ps[tA][lB] = p;
        p = (!diag || lA <= tB) ? __expf(s10 * SCALE - mzm[tB]) * mzz[tB] : 0.f; Ps[tB][lA] = p;
        p = (!diag || lB <= tB) ? __expf(s11 * SCALE - mzm[tB]) * mzz[tB] : 0.f; Ps[tB][lB] = p;
        __syncthreads();

#pragma unroll 8
        for (int tt = 0; tt < 32; ++tt) {
            float p0 = Ps[tt][tA];
            float p1 = Ps[tt][tB];
#pragma unroll
            for (int j = 0; j < 8; ++j) {
                float v = vs[tt][j * 16 + tx];
                acc[0][j] += p0 * v;
                acc[1][j] += p1 * v;
            }
        }
    }

#pragma unroll
    for (int i = 0; i < 2; ++i) {
        int l = l0 + ty * 2 + i;
#pragma unroll
        for (int j = 0; j < 8; ++j) {
            int e = j * 16 + tx;
            out2[(long long)l * D + e * NH + n] = acc[i][j];
        }
    }
}

} // namespace

extern "C" void kernel_launch(void* const* d_in, const int* in_sizes, int n_in,
                              void* d_out, int out_size, void* d_ws, size_t ws_size,
                              hipStream_t stream)
{
    (void)in_sizes; (void)n_in; (void)out_size; (void)ws_size;
    const float* h    = (const float*)d_in[0];
    const float* fr   = (const float*)d_in[1];
    // d_in[2] = mask: causal tril(0 / -1e9); causality applied analytically.
    const float* wdkv = (const float*)d_in[3];
    const float* wuk  = (const float*)d_in[4];
    const float* wuv  = (const float*)d_in[5];
    const float* wdq  = (const float*)d_in[6];
    const float* wuq  = (const float*)d_in[7];
    const float* wqr  = (const float*)d_in[8];
    const float* wkr  = (const float*)d_in[9];
    const float* wo   = (const float*)d_in[10];
    float* out = (float*)d_out;

    float* p     = (float*)d_ws;
    float* c_kv  = p; p += (long long)T * DC;
    float* c_q   = p; p += (long long)T * DC;
    float* krt   = p; p += (long long)T * DRH;
    float* qb    = p; p += (long long)NH * T * QK;
    float* kb    = p; p += (long long)NH * T * QK;
    float* vb    = p; p += (long long)NH * T * DH;
    float* mrow  = p; p += (long long)NH * T;
    float* zrow  = p; p += (long long)NH * T;
    float* attn2 = p; p += (long long)T * D;

    // 1-2: latents
    gemm_nt<128,128,8,8><<<dim3(T/128, DC/128, 1), 256, 0, stream>>>(
        h, wdkv, c_kv, D, D, D, DC, 0, 0, 0);
    gemm_nt<128,128,8,8><<<dim3(T/128, DC/128, 1), 256, 0, stream>>>(
        h, wdq, c_q, D, D, D, DC, 0, 0, 0);
    // 3: k_r raw
    gemm_nt<64,64,4,4><<<dim3(T/64, 1, 1), 256, 0, stream>>>(
        h, wkr, krt, D, D, D, DRH, 0, 0, 0);
    // 4: k_c into kb[:, :, 0:128]
    gemm_nt<128,128,8,8><<<dim3(T/128, 1, NH), 256, 0, stream>>>(
        c_kv, wuk, kb, DC, DC, NH * DC, QK, 0, DC, (long long)T * QK);
    // 5: v_c
    gemm_nt<128,128,8,8><<<dim3(T/128, 1, NH), 256, 0, stream>>>(
        c_kv, wuv, vb, DC, DC, NH * DC, DH, 0, DC, (long long)T * DH);
    // 6: q_c into qb[:, :, 0:128]
    gemm_nt<128,128,8,8><<<dim3(T/128, 1, NH), 256, 0, stream>>>(
        c_q, wuq, qb, DC, DC, NH * DC, QK, 0, DC, (long long)T * QK);
    // 7: q_r raw into qb[:, :, 128:192]
    gemm_nt<64,64,4,4><<<dim3(T/64, 1, NH), 256, 0, stream>>>(
        c_q, wqr, qb + DH, DC, DC, NH * DC, QK, 0, DC, (long long)T * QK);
    // 8-9: RoPE
    rope_q<<<dim3(NH * T * 32 / 256), 256, 0, stream>>>(qb, fr);
    rope_k<<<dim3(T * 32 / 256), 256, 0, stream>>>(krt, kb, fr);
    // 10: softmax stats
    row_stats<<<dim3(T / 32, NH), 256, 0, stream>>>(qb, kb, mrow, zrow);
    // 11: transposed PV into attn2[l, e*16+n]
    attn_pv<<<dim3(T / 32, NH), 256, 0, stream>>>(qb, kb, vb, mrow, zrow, attn2);
    // 12: final projection
    gemm_nt<128,128,8,8><<<dim3(T/128, D/128, 1), 256, 0, stream>>>(
        attn2, wo, out, D, D, DH * NH, D, 0, 0, 0);
}

// Round 2
// 645.598 us; speedup vs baseline: 5.9835x; 5.9835x over previous
//
#include <hip/hip_runtime.h>
#include <hip/hip_bf16.h>
#include <math.h>

// MLA forward, bf16 MFMA pipeline (fp32 accumulation everywhere).
// Stages:
//   cast_all: h + 7 weights fp32->bf16 ; wo_permute: w_o[d,e,n] -> wob[d, n*128+e] bf16
//   MFMA NT-GEMMs: c_kv, c_q (bf16), krt (fp32), k_c->kh, v_c->vbh, q_c->qh, q_r->qh[128:]
//   rope_q (in-place bf16), rope_k (krt fp32 -> kh bf16, /16, broadcast heads)
//   vtrans: vbh[n][t][e] -> vt[n][e][t]
//   row_stats: MFMA QK^T, online softmax stats per (n,t) over l<=t
//   attn_pv:   MFMA S^T = K@Q^T, P^T via LDS layout swap, out2[l][n*128+e] += P^T V
//   final MFMA GEMM: d_out = attn2 @ wob^T (fp32 out)

namespace {

constexpr int T   = 2048;
constexpr int D   = 2048;
constexpr int NH  = 16;
constexpr int DH  = 128;
constexpr int DRH = 64;
constexpr int DC  = 512;
constexpr int QK  = 192;
constexpr float SCALE = 0.07216878364870322f; // 1/sqrt(192)

typedef __attribute__((ext_vector_type(8))) short short8;
typedef __attribute__((ext_vector_type(4))) float f32x4;

#define MFMA16(a, b, c) __builtin_amdgcn_mfma_f32_16x16x32_bf16((a), (b), (c), 0, 0, 0)

__device__ __forceinline__ unsigned short f2b(float x) {
    unsigned u = __float_as_uint(x);
    unsigned r = (u + 0x7FFFu + ((u >> 16) & 1u)) >> 16;
    return (unsigned short)r;
}
__device__ __forceinline__ float b2f(unsigned short s) {
    return __uint_as_float(((unsigned)s) << 16);
}

// ---------------- fused fp32 -> bf16 cast of h + 7 weight tensors ----------------
constexpr long long SZ_H    = (long long)T * D;          // 4194304
constexpr long long SZ_DKV  = (long long)DC * D;         // 1048576
constexpr long long SZ_UK   = (long long)DH * NH * DC;   // 1048576
constexpr long long SZ_UV   = SZ_UK;
constexpr long long SZ_DQ   = SZ_DKV;
constexpr long long SZ_UQ   = SZ_UK;
constexpr long long SZ_QR   = (long long)DRH * NH * DC;  // 524288
constexpr long long SZ_KR   = (long long)DRH * D;        // 131072
constexpr long long C0 = SZ_H;
constexpr long long C1 = C0 + SZ_DKV;
constexpr long long C2 = C1 + SZ_UK;
constexpr long long C3 = C2 + SZ_UV;
constexpr long long C4 = C3 + SZ_DQ;
constexpr long long C5 = C4 + SZ_UQ;
constexpr long long C6 = C5 + SZ_QR;
constexpr long long C7 = C6 + SZ_KR;  // 10485760 total

__global__ __launch_bounds__(256) void cast_all(
    const float* __restrict__ h,   const float* __restrict__ wdkv,
    const float* __restrict__ wuk, const float* __restrict__ wuv,
    const float* __restrict__ wdq, const float* __restrict__ wuq,
    const float* __restrict__ wqr, const float* __restrict__ wkr,
    unsigned short* __restrict__ hb,   unsigned short* __restrict__ dkvb,
    unsigned short* __restrict__ ukb,  unsigned short* __restrict__ uvb,
    unsigned short* __restrict__ dqb,  unsigned short* __restrict__ uqb,
    unsigned short* __restrict__ qrb,  unsigned short* __restrict__ krb)
{
    long long i4 = ((long long)blockIdx.x * 256 + threadIdx.x) * 4;
    const float* src; unsigned short* dst; long long off;
    if      (i4 < C0) { src = h;    dst = hb;   off = i4; }
    else if (i4 < C1) { src = wdkv; dst = dkvb; off = i4 - C0; }
    else if (i4 < C2) { src = wuk;  dst = ukb;  off = i4 - C1; }
    else if (i4 < C3) { src = wuv;  dst = uvb;  off = i4 - C2; }
    else if (i4 < C4) { src = wdq;  dst = dqb;  off = i4 - C3; }
    else if (i4 < C5) { src = wuq;  dst = uqb;  off = i4 - C4; }
    else if (i4 < C6) { src = wqr;  dst = qrb;  off = i4 - C5; }
    else              { src = wkr;  dst = krb;  off = i4 - C6; }
    float4 v = *(const float4*)(src + off);
    unsigned lo = (unsigned)f2b(v.x) | ((unsigned)f2b(v.y) << 16);
    unsigned hi = (unsigned)f2b(v.z) | ((unsigned)f2b(v.w) << 16);
    uint2 pk; pk.x = lo; pk.y = hi;
    *(uint2*)(dst + off) = pk;
}

// wob[d][n*128 + e] = bf16(wo[d][e*16 + n]) ; one block per row d
__global__ __launch_bounds__(256) void wo_permute(const float* __restrict__ wo,
                                                  unsigned short* __restrict__ wob)
{
    __shared__ float row[2048];
    int d = blockIdx.x;
    const float* src = wo + (long long)d * 2048;
#pragma unroll
    for (int i = 0; i < 8; ++i) row[threadIdx.x + i * 256] = src[threadIdx.x + i * 256];
    __syncthreads();
    unsigned short* dst = wob + (long long)d * 2048;
#pragma unroll
    for (int i = 0; i < 8; ++i) {
        int j = threadIdx.x + i * 256;
        int n = j >> 7, e = j & 127;
        dst[j] = f2b(row[e * 16 + n]);
    }
}

// ---------------- bf16 MFMA NT GEMM: C[M,N] = A[M,K] @ B[N,K]^T ----------------
// grid (M/BM, N/BN, batch), 256 threads (4 waves). 16x16x32 bf16 MFMA.
template<int BM, int BN, int WM, int WN, bool OUTB>
__global__ __launch_bounds__(256) void gemm_bf16(
    const unsigned short* __restrict__ A, const unsigned short* __restrict__ B,
    void* __restrict__ C, int K, int lda, int ldb, int ldc,
    long long sB, long long sC)
{
    constexpr int MT = WM / 16, NT = WN / 16;
    constexpr int WX = BN / WN;
    __shared__ unsigned short As[BM * 40];
    __shared__ unsigned short Bs[BN * 40];
    const int tid = (int)threadIdx.x;
    const int wave = tid >> 6, lane = tid & 63;
    const int q = lane >> 4, c = lane & 15;
    const int wm = (wave / WX) * WM, wn = (wave % WX) * WN;
    const int m0 = (int)blockIdx.x * BM, n0 = (int)blockIdx.y * BN;
    const unsigned short* Bb = B + (long long)blockIdx.z * sB;

    f32x4 acc[MT][NT];
#pragma unroll
    for (int i = 0; i < MT; ++i)
#pragma unroll
        for (int j = 0; j < NT; ++j) acc[i][j] = (f32x4){0.f, 0.f, 0.f, 0.f};

    for (int k0 = 0; k0 < K; k0 += 32) {
        __syncthreads();
#pragma unroll
        for (int i = 0; i < (BM * 4) / 256; ++i) {
            int ch = tid + i * 256;
            int r = ch >> 2, cc = ch & 3;
            *(short8*)&As[r * 40 + cc * 8] =
                *(const short8*)&A[(long long)(m0 + r) * lda + k0 + cc * 8];
        }
#pragma unroll
        for (int i = 0; i < (BN * 4) / 256; ++i) {
            int ch = tid + i * 256;
            int r = ch >> 2, cc = ch & 3;
            *(short8*)&Bs[r * 40 + cc * 8] =
                *(const short8*)&Bb[(long long)(n0 + r) * ldb + k0 + cc * 8];
        }
        __syncthreads();
        short8 af[MT], bf_[NT];
#pragma unroll
        for (int i = 0; i < MT; ++i) af[i] = *(const short8*)&As[(wm + i * 16 + c) * 40 + q * 8];
#pragma unroll
        for (int j = 0; j < NT; ++j) bf_[j] = *(const short8*)&Bs[(wn + j * 16 + c) * 40 + q * 8];
#pragma unroll
        for (int i = 0; i < MT; ++i)
#pragma unroll
            for (int j = 0; j < NT; ++j)
                acc[i][j] = MFMA16(af[i], bf_[j], acc[i][j]);
    }
    long long cb = (long long)blockIdx.z * sC;
#pragma unroll
    for (int i = 0; i < MT; ++i)
#pragma unroll
        for (int j = 0; j < NT; ++j) {
            int rbase = m0 + wm + i * 16 + q * 4;
            int col = n0 + wn + j * 16 + c;
#pragma unroll
            for (int rr = 0; rr < 4; ++rr) {
                long long off = cb + (long long)(rbase + rr) * ldc + col;
                if (OUTB) ((unsigned short*)C)[off] = f2b(acc[i][j][rr]);
                else      ((float*)C)[off] = acc[i][j][rr];
            }
        }
}

// ---------------- RoPE ----------------
// qh[n][t][128+j], [160+j] rotated in place (bf16). NH*T*32 threads.
__global__ __launch_bounds__(256) void rope_q(unsigned short* __restrict__ qh,
                                              const float* __restrict__ fr)
{
    int idx = (int)blockIdx.x * 256 + (int)threadIdx.x;
    int j = idx & 31;
    int t = (idx >> 5) & (T - 1);
    int n = idx >> 16;
    float sn, cs;
    sincosf(fr[t * 32 + j], &sn, &cs);
    long long base = ((long long)(n * T + t)) * QK + 128 + j;
    float x0 = b2f(qh[base]);
    float x1 = b2f(qh[base + 32]);
    qh[base]      = f2b(x0 * cs - x1 * sn);
    qh[base + 32] = f2b(x0 * sn + x1 * cs);
}

// krt fp32 [t][64] -> kh bf16 [n][t][128+j],[160+j], scaled 1/16, broadcast. T*32 threads.
__global__ __launch_bounds__(256) void rope_k(const float* __restrict__ krt,
                                              unsigned short* __restrict__ kh,
                                              const float* __restrict__ fr)
{
    int idx = (int)blockIdx.x * 256 + (int)threadIdx.x;
    int j = idx & 31;
    int t = idx >> 5;
    float sn, cs;
    sincosf(fr[t * 32 + j], &sn, &cs);
    float x0 = krt[t * 64 + j];
    float x1 = krt[t * 64 + 32 + j];
    unsigned short y0 = f2b((x0 * cs - x1 * sn) * (1.0f / 16.0f));
    unsigned short y1 = f2b((x0 * sn + x1 * cs) * (1.0f / 16.0f));
#pragma unroll
    for (int n = 0; n < NH; ++n) {
        long long base = ((long long)(n * T + t)) * QK + 128 + j;
        kh[base]      = y0;
        kh[base + 32] = y1;
    }
}

// vbh[n][t][e] -> vt[n][e][t], 32x32 tiles
__global__ __launch_bounds__(256) void vtrans(const unsigned short* __restrict__ vbh,
                                              unsigned short* __restrict__ vt)
{
    __shared__ unsigned short ts[32][33];
    int t0 = (int)blockIdx.x * 32, e0 = (int)blockIdx.y * 32, n = (int)blockIdx.z;
    int tid = (int)threadIdx.x;
    int r = tid >> 3, cq = (tid & 7) * 4;
    const unsigned short* src = vbh + ((long long)(n * T + t0 + r)) * DH + e0 + cq;
#pragma unroll
    for (int i = 0; i < 4; ++i) ts[r][cq + i] = src[i];
    __syncthreads();
    unsigned short* dst = vt + ((long long)(n * DH + e0 + r)) * T + t0 + cq;
#pragma unroll
    for (int i = 0; i < 4; ++i) dst[i] = ts[cq + i][r];
}

// ---------------- Pass A: softmax stats (m, 1/z) per (n,t) ----------------
// grid (T/64, NH), 256 thr; wave owns 16 t-rows, MFMA QK^T, online stats.
__global__ __launch_bounds__(256) void row_stats(const unsigned short* __restrict__ qh,
                                                 const unsigned short* __restrict__ kh,
                                                 float* __restrict__ mrow,
                                                 float* __restrict__ zrow)
{
    int n = (int)blockIdx.y;
    int wave = (int)threadIdx.x >> 6, lane = (int)threadIdx.x & 63;
    int q = lane >> 4, c = lane & 15;
    int tb = (int)blockIdx.x * 64 + wave * 16;

    const unsigned short* qp = qh + ((long long)(n * T + tb + c)) * QK;
    short8 af[6];
#pragma unroll
    for (int f = 0; f < 6; ++f) af[f] = *(const short8*)(qp + f * 32 + q * 8);

    float m[4], z[4];
#pragma unroll
    for (int r = 0; r < 4; ++r) { m[r] = -1e30f; z[r] = 0.f; }

    int ltiles = (int)blockIdx.x * 4 + 4;
    const unsigned short* kbase = kh + ((long long)n * T) * QK;
    for (int lt = 0; lt < ltiles; ++lt) {
        const unsigned short* kp = kbase + ((long long)(lt * 16 + c)) * QK + q * 8;
        f32x4 d = (f32x4){0.f, 0.f, 0.f, 0.f};
#pragma unroll
        for (int f = 0; f < 6; ++f) {
            short8 bf_ = *(const short8*)(kp + f * 32);
            d = MFMA16(af[f], bf_, d);
        }
        int l = lt * 16 + c;
#pragma unroll
        for (int r = 0; r < 4; ++r) {
            int t = tb + q * 4 + r;
            if (l <= t) {
                float s = d[r] * SCALE;
                if (s > m[r]) { z[r] = z[r] * __expf(m[r] - s) + 1.f; m[r] = s; }
                else          { z[r] += __expf(s - m[r]); }
            }
        }
    }
#pragma unroll
    for (int off = 1; off < 16; off <<= 1) {
#pragma unroll
        for (int r = 0; r < 4; ++r) {
            float mo = __shfl_xor(m[r], off);
            float zo = __shfl_xor(z[r], off);
            float mm = fmaxf(m[r], mo);
            z[r] = z[r] * __expf(m[r] - mm) + zo * __expf(mo - mm);
            m[r] = mm;
        }
    }
    if (c == 0) {
#pragma unroll
        for (int r = 0; r < 4; ++r) {
            int t = tb + q * 4 + r;
            mrow[n * T + t] = m[r];
            zrow[n * T + t] = 1.0f / z[r];
        }
    }
}

// ---------------- Pass B: attn2[l][n*128+e] = sum_t P[t,l] V[t,e] ----------------
// grid (T/64, NH), 256 thr. Wave owns 16 l-rows; block loops t-tiles of 32.
__global__ __launch_bounds__(256) void attn_pv(const unsigned short* __restrict__ kh,
                                               const unsigned short* __restrict__ qh,
                                               const unsigned short* __restrict__ vt,
                                               const float* __restrict__ mrow,
                                               const float* __restrict__ zrow,
                                               unsigned short* __restrict__ attn2)
{
    int n = (int)blockIdx.y;
    int lbase = (int)blockIdx.x * 64;
    int tid = (int)threadIdx.x, wave = tid >> 6, lane = tid & 63;
    int q = lane >> 4, c = lane & 15;
    int lb = lbase + wave * 16;

    __shared__ unsigned short Qs[32 * 200];
    __shared__ unsigned short Vs[128 * 40];
    __shared__ unsigned short Ps[4][16 * 40];
    __shared__ float ms[32], zs[32];

    const unsigned short* kp = kh + ((long long)(n * T + lb + c)) * QK;
    short8 kf[6];
#pragma unroll
    for (int f = 0; f < 6; ++f) kf[f] = *(const short8*)(kp + f * 32 + q * 8);

    f32x4 acc[8];
#pragma unroll
    for (int e = 0; e < 8; ++e) acc[e] = (f32x4){0.f, 0.f, 0.f, 0.f};

    for (int t0 = lbase; t0 < T; t0 += 32) {
        __syncthreads();
        {
            const unsigned short* qp = qh + ((long long)(n * T + t0)) * QK;
#pragma unroll
            for (int i = 0; i < 3; ++i) {
                int ch = tid + i * 256;            // 768 chunks: 32 rows x 24
                int r = ch / 24, cc = ch % 24;
                *(short8*)&Qs[r * 200 + cc * 8] = *(const short8*)(qp + r * QK + cc * 8);
            }
            const unsigned short* vp = vt + ((long long)(n * DH)) * T + t0;
#pragma unroll
            for (int i = 0; i < 2; ++i) {
                int ch = tid + i * 256;            // 512 chunks: 128 rows x 4
                int r = ch >> 2, cc = ch & 3;
                *(short8*)&Vs[r * 40 + cc * 8] = *(const short8*)(vp + (long long)r * T + cc * 8);
            }
            if (tid < 32) { ms[tid] = mrow[n * T + t0 + tid]; zs[tid] = zrow[n * T + t0 + tid]; }
        }
        __syncthreads();
#pragma unroll
        for (int th = 0; th < 2; ++th) {
            f32x4 d = (f32x4){0.f, 0.f, 0.f, 0.f};
#pragma unroll
            for (int f = 0; f < 6; ++f) {
                short8 bq = *(const short8*)&Qs[(th * 16 + c) * 200 + f * 32 + q * 8];
                d = MFMA16(kf[f], bq, d);
            }
            int t = t0 + th * 16 + c;
            float mm = ms[th * 16 + c], zz = zs[th * 16 + c];
#pragma unroll
            for (int r = 0; r < 4; ++r) {
                int l = lb + q * 4 + r;
                float p = (t >= l) ? __expf(d[r] * SCALE - mm) * zz : 0.f;
                Ps[wave][(q * 4 + r) * 40 + th * 16 + c] = f2b(p);
            }
        }
        __syncthreads();
        short8 pf = *(const short8*)&Ps[wave][c * 40 + q * 8];
#pragma unroll
        for (int et = 0; et < 8; ++et) {
            short8 vf = *(const short8*)&Vs[(et * 16 + c) * 40 + q * 8];
            acc[et] = MFMA16(pf, vf, acc[et]);
        }
    }
#pragma unroll
    for (int et = 0; et < 8; ++et)
#pragma unroll
        for (int r = 0; r < 4; ++r) {
            int l = lb + q * 4 + r;
            attn2[(long long)l * D + n * 128 + et * 16 + c] = f2b(acc[et][r]);
        }
}

} // namespace

extern "C" void kernel_launch(void* const* d_in, const int* in_sizes, int n_in,
                              void* d_out, int out_size, void* d_ws, size_t ws_size,
                              hipStream_t stream)
{
    (void)in_sizes; (void)n_in; (void)out_size; (void)ws_size;
    const float* h    = (const float*)d_in[0];
    const float* fr   = (const float*)d_in[1];
    const float* wdkv = (const float*)d_in[3];
    const float* wuk  = (const float*)d_in[4];
    const float* wuv  = (const float*)d_in[5];
    const float* wdq  = (const float*)d_in[6];
    const float* wuq  = (const float*)d_in[7];
    const float* wqr  = (const float*)d_in[8];
    const float* wkr  = (const float*)d_in[9];
    const float* wo   = (const float*)d_in[10];
    float* out = (float*)d_out;

    char* p = (char*)d_ws;
    auto alloc = [&](long long bytes) { char* r = p; p += (bytes + 255) & ~255LL; return r; };
    unsigned short* hb    = (unsigned short*)alloc(SZ_H * 2);
    unsigned short* dkvb  = (unsigned short*)alloc(SZ_DKV * 2);
    unsigned short* ukb   = (unsigned short*)alloc(SZ_UK * 2);
    unsigned short* uvb   = (unsigned short*)alloc(SZ_UV * 2);
    unsigned short* dqb   = (unsigned short*)alloc(SZ_DQ * 2);
    unsigned short* uqb   = (unsigned short*)alloc(SZ_UQ * 2);
    unsigned short* qrb   = (unsigned short*)alloc(SZ_QR * 2);
    unsigned short* krb   = (unsigned short*)alloc(SZ_KR * 2);
    unsigned short* wob   = (unsigned short*)alloc((long long)D * D * 2);
    unsigned short* ckvb  = (unsigned short*)alloc((long long)T * DC * 2);
    unsigned short* cqb   = (unsigned short*)alloc((long long)T * DC * 2);
    float*          krt   = (float*)alloc((long long)T * DRH * 4);
    unsigned short* qhb   = (unsigned short*)alloc((long long)NH * T * QK * 2);
    unsigned short* khb   = (unsigned short*)alloc((long long)NH * T * QK * 2);
    unsigned short* vbh   = (unsigned short*)alloc((long long)NH * T * DH * 2);
    unsigned short* vtb   = (unsigned short*)alloc((long long)NH * T * DH * 2);
    float*          mrow  = (float*)alloc((long long)NH * T * 4);
    float*          zrow  = (float*)alloc((long long)NH * T * 4);
    unsigned short* attn2 = (unsigned short*)alloc((long long)T * D * 2);

    // casts
    cast_all<<<dim3((unsigned)(C7 / 1024)), 256, 0, stream>>>(
        h, wdkv, wuk, wuv, wdq, wuq, wqr, wkr, hb, dkvb, ukb, uvb, dqb, uqb, qrb, krb);
    wo_permute<<<dim3(D), 256, 0, stream>>>(wo, wob);

    // latents
    gemm_bf16<128,128,64,64,true><<<dim3(T/128, DC/128, 1), 256, 0, stream>>>(
        hb, dkvb, ckvb, D, D, D, DC, 0, 0);
    gemm_bf16<128,128,64,64,true><<<dim3(T/128, DC/128, 1), 256, 0, stream>>>(
        hb, dqb, cqb, D, D, D, DC, 0, 0);
    // k_r raw (fp32 out)
    gemm_bf16<128,64,32,64,false><<<dim3(T/128, 1, 1), 256, 0, stream>>>(
        hb, krb, krt, D, D, D, DRH, 0, 0);
    // up-projections (batched over heads; B row stride NH*DC, head offset DC)
    gemm_bf16<128,128,64,64,true><<<dim3(T/128, 1, NH), 256, 0, stream>>>(
        ckvb, ukb, khb, DC, DC, NH*DC, QK, DC, (long long)T * QK);
    gemm_bf16<128,128,64,64,true><<<dim3(T/128, 1, NH), 256, 0, stream>>>(
        ckvb, uvb, vbh, DC, DC, NH*DC, DH, DC, (long long)T * DH);
    gemm_bf16<128,128,64,64,true><<<dim3(T/128, 1, NH), 256, 0, stream>>>(
        cqb, uqb, qhb, DC, DC, NH*DC, QK, DC, (long long)T * QK);
    gemm_bf16<128,64,32,64,true><<<dim3(T/128, 1, NH), 256, 0, stream>>>(
        cqb, qrb, qhb + DH, DC, DC, NH*DC, QK, DC, (long long)T * QK);

    // rope + v transpose
    rope_q<<<dim3(NH * T * 32 / 256), 256, 0, stream>>>(qhb, fr);
    rope_k<<<dim3(T * 32 / 256), 256, 0, stream>>>(krt, khb, fr);
    vtrans<<<dim3(T/32, DH/32, NH), 256, 0, stream>>>(vbh, vtb);

    // attention
    row_stats<<<dim3(T/64, NH), 256, 0, stream>>>(qhb, khb, mrow, zrow);
    attn_pv<<<dim3(T/64, NH), 256, 0, stream>>>(khb, qhb, vtb, mrow, zrow, attn2);

    // final projection (fp32 out)
    gemm_bf16<128,128,64,64,false><<<dim3(T/128, D/128, 1), 256, 0, stream>>>(
        attn2, wob, out, D, D, D, D, 0, 0);
}

// Round 3
// 554.574 us; speedup vs baseline: 6.9656x; 1.1641x over previous
//
#include <hip/hip_runtime.h>
#include <hip/hip_bf16.h>
#include <math.h>

// MLA forward, bf16 MFMA pipeline v3.
//  - GEMMs: global_load_lds width=16 staging (m97 pattern), unpadded [B][32] LDS tiles.
//  - Softmax: max-free (logits are O(1); exp overflow-safe) -> z mergeable by atomicAdd
//    -> causal work split across grid.z for load balance in both attention passes.
//  - attn_pv: K-frags in registers, 64-wide t-tiles, 4+8 independent MFMA chains,
//    53.5 KB LDS (3 blocks/CU), t-range split over 2 chunks into bf16 partial buffers
//    (overlaid on dead hb/w_dkv/w_uk/w_uv/w_dq region), summed by sum_cast.

namespace {

constexpr int T   = 2048;
constexpr int D   = 2048;
constexpr int NH  = 16;
constexpr int DH  = 128;
constexpr int DRH = 64;
constexpr int DC  = 512;
constexpr int QK  = 192;
constexpr float SCALE = 0.07216878364870322f; // 1/sqrt(192)

typedef __attribute__((ext_vector_type(8))) short short8;
typedef __attribute__((ext_vector_type(4))) float f32x4;

#define MFMA16(a, b, c) __builtin_amdgcn_mfma_f32_16x16x32_bf16((a), (b), (c), 0, 0, 0)

__device__ __forceinline__ unsigned short f2b(float x) {
    unsigned u = __float_as_uint(x);
    unsigned r = (u + 0x7FFFu + ((u >> 16) & 1u)) >> 16;
    return (unsigned short)r;
}
__device__ __forceinline__ float b2f(unsigned short s) {
    return __uint_as_float(((unsigned)s) << 16);
}

typedef __attribute__((address_space(1))) const unsigned int* gas_t;
typedef __attribute__((address_space(3))) unsigned int* las_t;
__device__ __forceinline__ void async16(const unsigned short* g, unsigned short* l) {
    __builtin_amdgcn_global_load_lds((gas_t)(const void*)g, (las_t)(void*)l, 16, 0, 0);
}

// ---------------- fused fp32 -> bf16 cast of h + 7 weight tensors ----------------
constexpr long long SZ_H    = (long long)T * D;
constexpr long long SZ_DKV  = (long long)DC * D;
constexpr long long SZ_UK   = (long long)DH * NH * DC;
constexpr long long SZ_UV   = SZ_UK;
constexpr long long SZ_DQ   = SZ_DKV;
constexpr long long SZ_UQ   = SZ_UK;
constexpr long long SZ_QR   = (long long)DRH * NH * DC;
constexpr long long SZ_KR   = (long long)DRH * D;
constexpr long long C0 = SZ_H;
constexpr long long C1 = C0 + SZ_DKV;
constexpr long long C2 = C1 + SZ_UK;
constexpr long long C3 = C2 + SZ_UV;
constexpr long long C4 = C3 + SZ_DQ;
constexpr long long C5 = C4 + SZ_UQ;
constexpr long long C6 = C5 + SZ_QR;
constexpr long long C7 = C6 + SZ_KR;  // 10485760

__global__ __launch_bounds__(256) void cast_all(
    const float* __restrict__ h,   const float* __restrict__ wdkv,
    const float* __restrict__ wuk, const float* __restrict__ wuv,
    const float* __restrict__ wdq, const float* __restrict__ wuq,
    const float* __restrict__ wqr, const float* __restrict__ wkr,
    unsigned short* __restrict__ hb,   unsigned short* __restrict__ dkvb,
    unsigned short* __restrict__ ukb,  unsigned short* __restrict__ uvb,
    unsigned short* __restrict__ dqb,  unsigned short* __restrict__ uqb,
    unsigned short* __restrict__ qrb,  unsigned short* __restrict__ krb)
{
    long long i4 = ((long long)blockIdx.x * 256 + threadIdx.x) * 4;
    const float* src; unsigned short* dst; long long off;
    if      (i4 < C0) { src = h;    dst = hb;   off = i4; }
    else if (i4 < C1) { src = wdkv; dst = dkvb; off = i4 - C0; }
    else if (i4 < C2) { src = wuk;  dst = ukb;  off = i4 - C1; }
    else if (i4 < C3) { src = wuv;  dst = uvb;  off = i4 - C2; }
    else if (i4 < C4) { src = wdq;  dst = dqb;  off = i4 - C3; }
    else if (i4 < C5) { src = wuq;  dst = uqb;  off = i4 - C4; }
    else if (i4 < C6) { src = wqr;  dst = qrb;  off = i4 - C5; }
    else              { src = wkr;  dst = krb;  off = i4 - C6; }
    float4 v = *(const float4*)(src + off);
    uint2 pk;
    pk.x = (unsigned)f2b(v.x) | ((unsigned)f2b(v.y) << 16);
    pk.y = (unsigned)f2b(v.z) | ((unsigned)f2b(v.w) << 16);
    *(uint2*)(dst + off) = pk;
}

// wob[d][n*128 + e] = bf16(wo[d][e*16 + n])
__global__ __launch_bounds__(256) void wo_permute(const float* __restrict__ wo,
                                                  unsigned short* __restrict__ wob)
{
    __shared__ float row[2048];
    int d = blockIdx.x;
    const float* src = wo + (long long)d * 2048;
#pragma unroll
    for (int i = 0; i < 8; ++i) row[threadIdx.x + i * 256] = src[threadIdx.x + i * 256];
    __syncthreads();
    unsigned short* dst = wob + (long long)d * 2048;
#pragma unroll
    for (int i = 0; i < 8; ++i) {
        int j = threadIdx.x + i * 256;
        int n = j >> 7, e = j & 127;
        dst[j] = f2b(row[e * 16 + n]);
    }
}

// ---------------- bf16 MFMA NT GEMM with global_load_lds staging ----------------
// C[M,N] = A[M,K] @ B[N,K]^T ; grid (M/BM, N/BN, batch); 256 threads (4 waves).
template<int BM, int BN, int WM, int WN, bool OUTB>
__global__ __launch_bounds__(256) void gemm_bf16(
    const unsigned short* __restrict__ A, const unsigned short* __restrict__ B,
    void* __restrict__ C, int K, int lda, int ldb, int ldc,
    long long sB, long long sC)
{
    constexpr int MT = WM / 16, NT = WN / 16;
    constexpr int WX = BN / WN;
    __shared__ unsigned short As[BM * 32];
    __shared__ unsigned short Bs[BN * 32];
    const int tid = (int)threadIdx.x;
    const int wave = tid >> 6, lane = tid & 63;
    const int q = lane >> 4, c = lane & 15;
    const int wm = (wave / WX) * WM, wn = (wave % WX) * WN;
    const int m0 = (int)blockIdx.x * BM, n0 = (int)blockIdx.y * BN;
    const unsigned short* Bb = B + (long long)blockIdx.z * sB;

    f32x4 acc[MT][NT];
#pragma unroll
    for (int i = 0; i < MT; ++i)
#pragma unroll
        for (int j = 0; j < NT; ++j) acc[i][j] = (f32x4){0.f, 0.f, 0.f, 0.f};

    for (int k0 = 0; k0 < K; k0 += 32) {
        __syncthreads();
#pragma unroll
        for (int i = 0; i < BM / 64; ++i) {
            int ch = tid + i * 256;
            async16(&A[(long long)(m0 + (ch >> 2)) * lda + k0 + (ch & 3) * 8],
                    &As[(i * 256 + wave * 64) * 8]);
        }
#pragma unroll
        for (int i = 0; i < BN / 64; ++i) {
            int ch = tid + i * 256;
            async16(&Bb[(long long)(n0 + (ch >> 2)) * ldb + k0 + (ch & 3) * 8],
                    &Bs[(i * 256 + wave * 64) * 8]);
        }
        __syncthreads();
        short8 af[MT], bfr[NT];
#pragma unroll
        for (int i = 0; i < MT; ++i) af[i] = *(const short8*)&As[(wm + i * 16 + c) * 32 + q * 8];
#pragma unroll
        for (int j = 0; j < NT; ++j) bfr[j] = *(const short8*)&Bs[(wn + j * 16 + c) * 32 + q * 8];
#pragma unroll
        for (int i = 0; i < MT; ++i)
#pragma unroll
            for (int j = 0; j < NT; ++j)
                acc[i][j] = MFMA16(af[i], bfr[j], acc[i][j]);
    }
    long long cb = (long long)blockIdx.z * sC;
#pragma unroll
    for (int i = 0; i < MT; ++i)
#pragma unroll
        for (int j = 0; j < NT; ++j) {
            int rbase = m0 + wm + i * 16 + q * 4;
            int col = n0 + wn + j * 16 + c;
#pragma unroll
            for (int rr = 0; rr < 4; ++rr) {
                long long off = cb + (long long)(rbase + rr) * ldc + col;
                if (OUTB) ((unsigned short*)C)[off] = f2b(acc[i][j][rr]);
                else      ((float*)C)[off] = acc[i][j][rr];
            }
        }
}

// ---------------- RoPE ----------------
__global__ __launch_bounds__(256) void rope_q(unsigned short* __restrict__ qh,
                                              const float* __restrict__ fr)
{
    int idx = (int)blockIdx.x * 256 + (int)threadIdx.x;
    int j = idx & 31;
    int t = (idx >> 5) & (T - 1);
    int n = idx >> 16;
    float sn, cs;
    sincosf(fr[t * 32 + j], &sn, &cs);
    long long base = ((long long)(n * T + t)) * QK + 128 + j;
    float x0 = b2f(qh[base]);
    float x1 = b2f(qh[base + 32]);
    qh[base]      = f2b(x0 * cs - x1 * sn);
    qh[base + 32] = f2b(x0 * sn + x1 * cs);
}

__global__ __launch_bounds__(256) void rope_k(const float* __restrict__ krt,
                                              unsigned short* __restrict__ kh,
                                              const float* __restrict__ fr)
{
    int idx = (int)blockIdx.x * 256 + (int)threadIdx.x;
    int j = idx & 31;
    int t = idx >> 5;
    float sn, cs;
    sincosf(fr[t * 32 + j], &sn, &cs);
    float x0 = krt[t * 64 + j];
    float x1 = krt[t * 64 + 32 + j];
    unsigned short y0 = f2b((x0 * cs - x1 * sn) * (1.0f / 16.0f));
    unsigned short y1 = f2b((x0 * sn + x1 * cs) * (1.0f / 16.0f));
#pragma unroll
    for (int n = 0; n < NH; ++n) {
        long long base = ((long long)(n * T + t)) * QK + 128 + j;
        kh[base]      = y0;
        kh[base + 32] = y1;
    }
}

// vbh[n][t][e] -> vt[n][e][t]
__global__ __launch_bounds__(256) void vtrans(const unsigned short* __restrict__ vbh,
                                              unsigned short* __restrict__ vt)
{
    __shared__ unsigned short ts[32][33];
    int t0 = (int)blockIdx.x * 32, e0 = (int)blockIdx.y * 32, n = (int)blockIdx.z;
    int tid = (int)threadIdx.x;
    int r = tid >> 3, cq = (tid & 7) * 4;
    const unsigned short* src = vbh + ((long long)(n * T + t0 + r)) * DH + e0 + cq;
#pragma unroll
    for (int i = 0; i < 4; ++i) ts[r][cq + i] = src[i];
    __syncthreads();
    unsigned short* dst = vt + ((long long)(n * DH + e0 + r)) * T + t0 + cq;
#pragma unroll
    for (int i = 0; i < 4; ++i) dst[i] = ts[cq + i][r];
}

// ---------------- Pass A: z_t = sum_{l<=t} exp(s_tl)  (max-free, atomic merge) ----------------
// grid (T/64, NH, 4); 256 thr. Wave owns 16 t-rows (Q frags in regs); K staged in LDS.
__global__ __launch_bounds__(256) void row_stats(const unsigned short* __restrict__ qh,
                                                 const unsigned short* __restrict__ kh,
                                                 float* __restrict__ zrow)
{
    int tbi = (int)blockIdx.x, n = (int)blockIdx.y, chunk = (int)blockIdx.z;
    int tid = (int)threadIdx.x, wave = tid >> 6, lane = tid & 63;
    int q = lane >> 4, c = lane & 15;
    int tw = tbi * 64 + wave * 16;

    __shared__ unsigned short Ks[64 * 200];   // 64 K-rows, padded to 200 shorts

    const unsigned short* qp = qh + ((long long)(n * T + tw + c)) * QK;
    short8 af[6];
#pragma unroll
    for (int f = 0; f < 6; ++f) af[f] = *(const short8*)(qp + f * 32 + q * 8);

    float z[4] = {0.f, 0.f, 0.f, 0.f};
    const unsigned short* kbase = kh + (long long)n * T * QK;

    for (int lt = chunk; lt <= tbi; lt += 4) {
        __syncthreads();
        const unsigned short* kp = kbase + (long long)lt * 64 * QK;
#pragma unroll
        for (int i = 0; i < 6; ++i) {
            int ch = tid + i * 256;
            int r = ch / 24, cc = ch - r * 24;
            *(short8*)&Ks[r * 200 + cc * 8] = *(const short8*)(kp + r * 192 + cc * 8);
        }
        __syncthreads();
        f32x4 d[4];
#pragma unroll
        for (int ls = 0; ls < 4; ++ls) d[ls] = (f32x4){0.f, 0.f, 0.f, 0.f};
#pragma unroll
        for (int f = 0; f < 6; ++f)
#pragma unroll
            for (int ls = 0; ls < 4; ++ls) {
                short8 bfr = *(const short8*)&Ks[(ls * 16 + c) * 200 + f * 32 + q * 8];
                d[ls] = MFMA16(af[f], bfr, d[ls]);
            }
        if (lt == tbi) {
#pragma unroll
            for (int ls = 0; ls < 4; ++ls)
#pragma unroll
                for (int r = 0; r < 4; ++r) {
                    int l = lt * 64 + ls * 16 + c;
                    int t = tw + q * 4 + r;
                    if (l <= t) z[r] += __expf(d[ls][r] * SCALE);
                }
        } else {
#pragma unroll
            for (int ls = 0; ls < 4; ++ls)
#pragma unroll
                for (int r = 0; r < 4; ++r)
                    z[r] += __expf(d[ls][r] * SCALE);
        }
    }
#pragma unroll
    for (int off = 1; off < 16; off <<= 1)
#pragma unroll
        for (int r = 0; r < 4; ++r)
            z[r] += __shfl_xor(z[r], off);
    if (c == 0) {
#pragma unroll
        for (int r = 0; r < 4; ++r)
            atomicAdd(&zrow[n * T + tw + q * 4 + r], z[r]);
    }
}

// ---------------- Pass B: out[l][n*128+e] += sum_t P[t,l] V[t,e] (bf16 partials) ----------------
// grid (T/64, NH, 2); 256 thr. Wave owns 16 l-rows (K frags in regs); t split over chunks.
__global__ __launch_bounds__(256) void attn_pv(const unsigned short* __restrict__ kh,
                                               const unsigned short* __restrict__ qh,
                                               const unsigned short* __restrict__ vt,
                                               const float* __restrict__ zrow,
                                               unsigned short* __restrict__ outp)
{
    int li = 31 - (int)blockIdx.x;           // longest blocks first
    int n = (int)blockIdx.y, chunk = (int)blockIdx.z;
    int lbase = li * 64;
    int tid = (int)threadIdx.x, wave = tid >> 6, lane = tid & 63;
    int q = lane >> 4, c = lane & 15;
    int lb = lbase + wave * 16;

    __shared__ unsigned short Qs[64 * 200];  // 25600 B
    __shared__ unsigned short Vs[128 * 72];  // 18432 B
    __shared__ unsigned short Ps[4][16 * 72];//  9216 B
    __shared__ float zs[64];

    const unsigned short* kp = kh + ((long long)(n * T + lb + c)) * QK;
    short8 kf[6];
#pragma unroll
    for (int f = 0; f < 6; ++f) kf[f] = *(const short8*)(kp + f * 32 + q * 8);

    f32x4 acc[8];
#pragma unroll
    for (int et = 0; et < 8; ++et) acc[et] = (f32x4){0.f, 0.f, 0.f, 0.f};

    int nt = 32 - li;
    const unsigned short* vbase = vt + (long long)n * DH * T;

    for (int ti = chunk; ti < nt; ti += 2) {
        int t0 = lbase + ti * 64;
        __syncthreads();
        const unsigned short* qp = qh + ((long long)(n * T + t0)) * QK;
#pragma unroll
        for (int i = 0; i < 6; ++i) {
            int ch = tid + i * 256;
            int r = ch / 24, cc = ch - r * 24;
            *(short8*)&Qs[r * 200 + cc * 8] = *(const short8*)(qp + r * 192 + cc * 8);
        }
#pragma unroll
        for (int i = 0; i < 4; ++i) {
            int ch = tid + i * 256;
            int r = ch >> 3, cc = ch & 7;
            *(short8*)&Vs[r * 72 + cc * 8] = *(const short8*)(vbase + (long long)r * T + t0 + cc * 8);
        }
        if (tid < 64) zs[tid] = 1.0f / zrow[n * T + t0 + tid];
        __syncthreads();

        f32x4 d[4];
#pragma unroll
        for (int ts = 0; ts < 4; ++ts) d[ts] = (f32x4){0.f, 0.f, 0.f, 0.f};
#pragma unroll
        for (int f = 0; f < 6; ++f)
#pragma unroll
            for (int ts = 0; ts < 4; ++ts) {
                short8 bq = *(const short8*)&Qs[(ts * 16 + c) * 200 + f * 32 + q * 8];
                d[ts] = MFMA16(kf[f], bq, d[ts]);
            }
#pragma unroll
        for (int ts = 0; ts < 4; ++ts) {
            int t = t0 + ts * 16 + c;
            float zi = zs[ts * 16 + c];
#pragma unroll
            for (int r = 0; r < 4; ++r) {
                int l = lb + q * 4 + r;
                float p = (t >= l) ? __expf(d[ts][r] * SCALE) * zi : 0.f;
                Ps[wave][(q * 4 + r) * 72 + ts * 16 + c] = f2b(p);
            }
        }
        __syncthreads();
#pragma unroll
        for (int kt = 0; kt < 2; ++kt) {
            short8 pf = *(const short8*)&Ps[wave][c * 72 + kt * 32 + q * 8];
#pragma unroll
            for (int et = 0; et < 8; ++et) {
                short8 vf = *(const short8*)&Vs[(et * 16 + c) * 72 + kt * 32 + q * 8];
                acc[et] = MFMA16(pf, vf, acc[et]);
            }
        }
    }
    unsigned short* op = outp + (long long)chunk * T * D;
#pragma unroll
    for (int et = 0; et < 8; ++et)
#pragma unroll
        for (int r = 0; r < 4; ++r)
            op[(long long)(lb + q * 4 + r) * D + n * 128 + et * 16 + c] = f2b(acc[et][r]);
}

// attn2b = bf16(pva + pvb)
__global__ __launch_bounds__(256) void sum_cast(const unsigned short* __restrict__ a,
                                                const unsigned short* __restrict__ b,
                                                unsigned short* __restrict__ o)
{
    long long i = ((long long)blockIdx.x * 256 + threadIdx.x) * 8;
    short8 va = *(const short8*)(a + i);
    short8 vb = *(const short8*)(b + i);
    short8 vo;
#pragma unroll
    for (int j = 0; j < 8; ++j)
        vo[j] = (short)f2b(b2f((unsigned short)va[j]) + b2f((unsigned short)vb[j]));
    *(short8*)(o + i) = vo;
}

} // namespace

extern "C" void kernel_launch(void* const* d_in, const int* in_sizes, int n_in,
                              void* d_out, int out_size, void* d_ws, size_t ws_size,
                              hipStream_t stream)
{
    (void)in_sizes; (void)n_in; (void)out_size; (void)ws_size;
    const float* h    = (const float*)d_in[0];
    const float* fr   = (const float*)d_in[1];
    const float* wdkv = (const float*)d_in[3];
    const float* wuk  = (const float*)d_in[4];
    const float* wuv  = (const float*)d_in[5];
    const float* wdq  = (const float*)d_in[6];
    const float* wuq  = (const float*)d_in[7];
    const float* wqr  = (const float*)d_in[8];
    const float* wkr  = (const float*)d_in[9];
    const float* wo   = (const float*)d_in[10];
    float* out = (float*)d_out;

    char* p = (char*)d_ws;
    auto alloc = [&](long long bytes) { char* r = p; p += (bytes + 255) & ~255LL; return r; };
    unsigned short* hb    = (unsigned short*)alloc(SZ_H * 2);
    unsigned short* dkvb  = (unsigned short*)alloc(SZ_DKV * 2);
    unsigned short* ukb   = (unsigned short*)alloc(SZ_UK * 2);
    unsigned short* uvb   = (unsigned short*)alloc(SZ_UV * 2);
    unsigned short* dqb   = (unsigned short*)alloc(SZ_DQ * 2);
    unsigned short* uqb   = (unsigned short*)alloc(SZ_UQ * 2);
    unsigned short* qrb   = (unsigned short*)alloc(SZ_QR * 2);
    unsigned short* krb   = (unsigned short*)alloc(SZ_KR * 2);
    unsigned short* wob   = (unsigned short*)alloc((long long)D * D * 2);
    unsigned short* ckvb  = (unsigned short*)alloc((long long)T * DC * 2);
    unsigned short* cqb   = (unsigned short*)alloc((long long)T * DC * 2);
    float*          krt   = (float*)alloc((long long)T * DRH * 4);
    unsigned short* qhb   = (unsigned short*)alloc((long long)NH * T * QK * 2);
    unsigned short* khb   = (unsigned short*)alloc((long long)NH * T * QK * 2);
    unsigned short* vbh   = (unsigned short*)alloc((long long)NH * T * DH * 2);
    unsigned short* vtb   = (unsigned short*)alloc((long long)NH * T * DH * 2);
    float*          zrow  = (float*)alloc((long long)NH * T * 4);
    unsigned short* attn2 = (unsigned short*)alloc((long long)T * D * 2);
    // PV partial buffers (2 x T*D bf16 = 16 MB) overlay hb..dqb, all dead by attn_pv time.
    unsigned short* pvp   = hb;

    cast_all<<<dim3((unsigned)(C7 / 1024)), 256, 0, stream>>>(
        h, wdkv, wuk, wuv, wdq, wuq, wqr, wkr, hb, dkvb, ukb, uvb, dqb, uqb, qrb, krb);
    wo_permute<<<dim3(D), 256, 0, stream>>>(wo, wob);

    gemm_bf16<128,128,64,64,true><<<dim3(T/128, DC/128, 1), 256, 0, stream>>>(
        hb, dkvb, ckvb, D, D, D, DC, 0, 0);
    gemm_bf16<128,128,64,64,true><<<dim3(T/128, DC/128, 1), 256, 0, stream>>>(
        hb, dqb, cqb, D, D, D, DC, 0, 0);
    gemm_bf16<128,64,32,64,false><<<dim3(T/128, 1, 1), 256, 0, stream>>>(
        hb, krb, krt, D, D, D, DRH, 0, 0);
    gemm_bf16<128,128,64,64,true><<<dim3(T/128, 1, NH), 256, 0, stream>>>(
        ckvb, ukb, khb, DC, DC, NH*DC, QK, DC, (long long)T * QK);
    gemm_bf16<128,128,64,64,true><<<dim3(T/128, 1, NH), 256, 0, stream>>>(
        ckvb, uvb, vbh, DC, DC, NH*DC, DH, DC, (long long)T * DH);
    gemm_bf16<128,128,64,64,true><<<dim3(T/128, 1, NH), 256, 0, stream>>>(
        cqb, uqb, qhb, DC, DC, NH*DC, QK, DC, (long long)T * QK);
    gemm_bf16<128,64,32,64,true><<<dim3(T/128, 1, NH), 256, 0, stream>>>(
        cqb, qrb, qhb + DH, DC, DC, NH*DC, QK, DC, (long long)T * QK);

    rope_q<<<dim3(NH * T * 32 / 256), 256, 0, stream>>>(qhb, fr);
    rope_k<<<dim3(T * 32 / 256), 256, 0, stream>>>(krt, khb, fr);
    vtrans<<<dim3(T/32, DH/32, NH), 256, 0, stream>>>(vbh, vtb);

    hipMemsetAsync(zrow, 0, (long long)NH * T * 4, stream);
    row_stats<<<dim3(T/64, NH, 4), 256, 0, stream>>>(qhb, khb, zrow);
    attn_pv<<<dim3(T/64, NH, 2), 256, 0, stream>>>(khb, qhb, vtb, zrow, pvp);
    sum_cast<<<dim3(T * D / 2048), 256, 0, stream>>>(pvp, pvp + (long long)T * D, attn2);

    gemm_bf16<128,128,64,64,false><<<dim3(T/128, D/128, 1), 256, 0, stream>>>(
        attn2, wob, out, D, D, D, D, 0, 0);
}

// Round 4
// 486.414 us; speedup vs baseline: 7.9417x; 1.1401x over previous
//
#include <hip/hip_runtime.h>
#include <hip/hip_bf16.h>
#include <math.h>

// MLA forward, bf16 MFMA pipeline v4.
//  - attn passes: register-prefetch double-buffering (loads for tile i+1 issued
//    during compute of tile i), 2 barriers/iter, longest-blocks-first dispatch,
//    1/z folded into V (vtrans_scale), exp2-folded softmax scale, diag-only masking.
//  - GEMMs: m97-pattern global_load_lds width=16 staging (unchanged, known-good).

namespace {

constexpr int T   = 2048;
constexpr int D   = 2048;
constexpr int NH  = 16;
constexpr int DH  = 128;
constexpr int DRH = 64;
constexpr int DC  = 512;
constexpr int QK  = 192;
constexpr float SCALE = 0.07216878364870322f;           // 1/sqrt(192)
constexpr float SCL2E = 0.07216878364870322f * 1.4426950408889634f; // SCALE*log2(e)

typedef __attribute__((ext_vector_type(8))) short short8;
typedef __attribute__((ext_vector_type(4))) float f32x4;

#define MFMA16(a, b, c) __builtin_amdgcn_mfma_f32_16x16x32_bf16((a), (b), (c), 0, 0, 0)

__device__ __forceinline__ unsigned short f2b(float x) {
    unsigned u = __float_as_uint(x);
    unsigned r = (u + 0x7FFFu + ((u >> 16) & 1u)) >> 16;
    return (unsigned short)r;
}
__device__ __forceinline__ float b2f(unsigned short s) {
    return __uint_as_float(((unsigned)s) << 16);
}

typedef __attribute__((address_space(1))) const unsigned int* gas_t;
typedef __attribute__((address_space(3))) unsigned int* las_t;
__device__ __forceinline__ void async16(const unsigned short* g, unsigned short* l) {
    __builtin_amdgcn_global_load_lds((gas_t)(const void*)g, (las_t)(void*)l, 16, 0, 0);
}

// ---------------- fused fp32 -> bf16 cast of h + 7 weight tensors ----------------
constexpr long long SZ_H    = (long long)T * D;
constexpr long long SZ_DKV  = (long long)DC * D;
constexpr long long SZ_UK   = (long long)DH * NH * DC;
constexpr long long SZ_UV   = SZ_UK;
constexpr long long SZ_DQ   = SZ_DKV;
constexpr long long SZ_UQ   = SZ_UK;
constexpr long long SZ_QR   = (long long)DRH * NH * DC;
constexpr long long SZ_KR   = (long long)DRH * D;
constexpr long long C0 = SZ_H;
constexpr long long C1 = C0 + SZ_DKV;
constexpr long long C2 = C1 + SZ_UK;
constexpr long long C3 = C2 + SZ_UV;
constexpr long long C4 = C3 + SZ_DQ;
constexpr long long C5 = C4 + SZ_UQ;
constexpr long long C6 = C5 + SZ_QR;
constexpr long long C7 = C6 + SZ_KR;  // 10485760

__global__ __launch_bounds__(256) void cast_all(
    const float* __restrict__ h,   const float* __restrict__ wdkv,
    const float* __restrict__ wuk, const float* __restrict__ wuv,
    const float* __restrict__ wdq, const float* __restrict__ wuq,
    const float* __restrict__ wqr, const float* __restrict__ wkr,
    unsigned short* __restrict__ hb,   unsigned short* __restrict__ dkvb,
    unsigned short* __restrict__ ukb,  unsigned short* __restrict__ uvb,
    unsigned short* __restrict__ dqb,  unsigned short* __restrict__ uqb,
    unsigned short* __restrict__ qrb,  unsigned short* __restrict__ krb)
{
    long long i4 = ((long long)blockIdx.x * 256 + threadIdx.x) * 4;
    const float* src; unsigned short* dst; long long off;
    if      (i4 < C0) { src = h;    dst = hb;   off = i4; }
    else if (i4 < C1) { src = wdkv; dst = dkvb; off = i4 - C0; }
    else if (i4 < C2) { src = wuk;  dst = ukb;  off = i4 - C1; }
    else if (i4 < C3) { src = wuv;  dst = uvb;  off = i4 - C2; }
    else if (i4 < C4) { src = wdq;  dst = dqb;  off = i4 - C3; }
    else if (i4 < C5) { src = wuq;  dst = uqb;  off = i4 - C4; }
    else if (i4 < C6) { src = wqr;  dst = qrb;  off = i4 - C5; }
    else              { src = wkr;  dst = krb;  off = i4 - C6; }
    float4 v = *(const float4*)(src + off);
    uint2 pk;
    pk.x = (unsigned)f2b(v.x) | ((unsigned)f2b(v.y) << 16);
    pk.y = (unsigned)f2b(v.z) | ((unsigned)f2b(v.w) << 16);
    *(uint2*)(dst + off) = pk;
}

// wob[d][n*128 + e] = bf16(wo[d][e*16 + n])
__global__ __launch_bounds__(256) void wo_permute(const float* __restrict__ wo,
                                                  unsigned short* __restrict__ wob)
{
    __shared__ float row[2048];
    int d = blockIdx.x;
    const float* src = wo + (long long)d * 2048;
#pragma unroll
    for (int i = 0; i < 8; ++i) row[threadIdx.x + i * 256] = src[threadIdx.x + i * 256];
    __syncthreads();
    unsigned short* dst = wob + (long long)d * 2048;
#pragma unroll
    for (int i = 0; i < 8; ++i) {
        int j = threadIdx.x + i * 256;
        int n = j >> 7, e = j & 127;
        dst[j] = f2b(row[e * 16 + n]);
    }
}

// ---------------- bf16 MFMA NT GEMM with global_load_lds staging ----------------
template<int BM, int BN, int WM, int WN, bool OUTB>
__global__ __launch_bounds__(256) void gemm_bf16(
    const unsigned short* __restrict__ A, const unsigned short* __restrict__ B,
    void* __restrict__ C, int K, int lda, int ldb, int ldc,
    long long sB, long long sC)
{
    constexpr int MT = WM / 16, NT = WN / 16;
    constexpr int WX = BN / WN;
    __shared__ unsigned short As[BM * 32];
    __shared__ unsigned short Bs[BN * 32];
    const int tid = (int)threadIdx.x;
    const int wave = tid >> 6, lane = tid & 63;
    const int q = lane >> 4, c = lane & 15;
    const int wm = (wave / WX) * WM, wn = (wave % WX) * WN;
    const int m0 = (int)blockIdx.x * BM, n0 = (int)blockIdx.y * BN;
    const unsigned short* Bb = B + (long long)blockIdx.z * sB;

    f32x4 acc[MT][NT];
#pragma unroll
    for (int i = 0; i < MT; ++i)
#pragma unroll
        for (int j = 0; j < NT; ++j) acc[i][j] = (f32x4){0.f, 0.f, 0.f, 0.f};

    for (int k0 = 0; k0 < K; k0 += 32) {
        __syncthreads();
#pragma unroll
        for (int i = 0; i < BM / 64; ++i) {
            int ch = tid + i * 256;
            async16(&A[(long long)(m0 + (ch >> 2)) * lda + k0 + (ch & 3) * 8],
                    &As[(i * 256 + wave * 64) * 8]);
        }
#pragma unroll
        for (int i = 0; i < BN / 64; ++i) {
            int ch = tid + i * 256;
            async16(&Bb[(long long)(n0 + (ch >> 2)) * ldb + k0 + (ch & 3) * 8],
                    &Bs[(i * 256 + wave * 64) * 8]);
        }
        __syncthreads();
        short8 af[MT], bfr[NT];
#pragma unroll
        for (int i = 0; i < MT; ++i) af[i] = *(const short8*)&As[(wm + i * 16 + c) * 32 + q * 8];
#pragma unroll
        for (int j = 0; j < NT; ++j) bfr[j] = *(const short8*)&Bs[(wn + j * 16 + c) * 32 + q * 8];
#pragma unroll
        for (int i = 0; i < MT; ++i)
#pragma unroll
            for (int j = 0; j < NT; ++j)
                acc[i][j] = MFMA16(af[i], bfr[j], acc[i][j]);
    }
    long long cb = (long long)blockIdx.z * sC;
#pragma unroll
    for (int i = 0; i < MT; ++i)
#pragma unroll
        for (int j = 0; j < NT; ++j) {
            int rbase = m0 + wm + i * 16 + q * 4;
            int col = n0 + wn + j * 16 + c;
#pragma unroll
            for (int rr = 0; rr < 4; ++rr) {
                long long off = cb + (long long)(rbase + rr) * ldc + col;
                if (OUTB) ((unsigned short*)C)[off] = f2b(acc[i][j][rr]);
                else      ((float*)C)[off] = acc[i][j][rr];
            }
        }
}

// ---------------- RoPE ----------------
__global__ __launch_bounds__(256) void rope_q(unsigned short* __restrict__ qh,
                                              const float* __restrict__ fr)
{
    int idx = (int)blockIdx.x * 256 + (int)threadIdx.x;
    int j = idx & 31;
    int t = (idx >> 5) & (T - 1);
    int n = idx >> 16;
    float sn, cs;
    sincosf(fr[t * 32 + j], &sn, &cs);
    long long base = ((long long)(n * T + t)) * QK + 128 + j;
    float x0 = b2f(qh[base]);
    float x1 = b2f(qh[base + 32]);
    qh[base]      = f2b(x0 * cs - x1 * sn);
    qh[base + 32] = f2b(x0 * sn + x1 * cs);
}

__global__ __launch_bounds__(256) void rope_k(const float* __restrict__ krt,
                                              unsigned short* __restrict__ kh,
                                              const float* __restrict__ fr)
{
    int idx = (int)blockIdx.x * 256 + (int)threadIdx.x;
    int j = idx & 31;
    int t = idx >> 5;
    float sn, cs;
    sincosf(fr[t * 32 + j], &sn, &cs);
    float x0 = krt[t * 64 + j];
    float x1 = krt[t * 64 + 32 + j];
    unsigned short y0 = f2b((x0 * cs - x1 * sn) * (1.0f / 16.0f));
    unsigned short y1 = f2b((x0 * sn + x1 * cs) * (1.0f / 16.0f));
#pragma unroll
    for (int n = 0; n < NH; ++n) {
        long long base = ((long long)(n * T + t)) * QK + 128 + j;
        kh[base]      = y0;
        kh[base + 32] = y1;
    }
}

// vbh[n][t][e] -> vt[n][e][t] scaled by 1/z_t (fold softmax denominator into V)
__global__ __launch_bounds__(256) void vtrans(const unsigned short* __restrict__ vbh,
                                              const float* __restrict__ zrow,
                                              unsigned short* __restrict__ vt)
{
    __shared__ unsigned short ts[32][33];
    __shared__ float zi[32];
    int t0 = (int)blockIdx.x * 32, e0 = (int)blockIdx.y * 32, n = (int)blockIdx.z;
    int tid = (int)threadIdx.x;
    if (tid < 32) zi[tid] = 1.0f / zrow[n * T + t0 + tid];
    int r = tid >> 3, cq = (tid & 7) * 4;
    const unsigned short* src = vbh + ((long long)(n * T + t0 + r)) * DH + e0 + cq;
#pragma unroll
    for (int i = 0; i < 4; ++i) ts[r][cq + i] = src[i];
    __syncthreads();
    unsigned short* dst = vt + ((long long)(n * DH + e0 + r)) * T + t0 + cq;
#pragma unroll
    for (int i = 0; i < 4; ++i) dst[i] = f2b(b2f(ts[cq + i][r]) * zi[cq + i]);
}

// ---------------- Pass A: z_t = sum_{l<=t} exp(s_tl)  (max-free, atomic merge) ----------------
// grid (T/64, NH, 4); 256 thr. Longest blocks first; register-prefetch dbuf for K tiles.
__global__ __launch_bounds__(256) void row_stats(const unsigned short* __restrict__ qh,
                                                 const unsigned short* __restrict__ kh,
                                                 float* __restrict__ zrow)
{
    int tbi = 31 - (int)blockIdx.x;          // longest (tbi=31) first
    int n = (int)blockIdx.y, chunk = (int)blockIdx.z;
    int tid = (int)threadIdx.x, wave = tid >> 6, lane = tid & 63;
    int q = lane >> 4, c = lane & 15;
    int tw = tbi * 64 + wave * 16;

    __shared__ unsigned short Ks[64 * 200];

    const unsigned short* qp = qh + ((long long)(n * T + tw + c)) * QK;
    short8 af[6];
#pragma unroll
    for (int f = 0; f < 6; ++f) af[f] = *(const short8*)(qp + f * 32 + q * 8);

    float z[4] = {0.f, 0.f, 0.f, 0.f};
    const unsigned short* kbase = kh + (long long)n * T * QK;

    int kr = tid / 24 * 0; // (placeholder opt-out; indices computed inline)
    (void)kr;
    short8 kreg[6];
    int lt = chunk;
    if (lt <= tbi) {
        const unsigned short* kp = kbase + (long long)lt * 64 * QK;
#pragma unroll
        for (int i = 0; i < 6; ++i) {
            int ch = tid + i * 256;
            int r = ch / 24, cc = ch - r * 24;
            kreg[i] = *(const short8*)(kp + r * QK + cc * 8);
        }
    }
    for (; lt <= tbi; lt += 4) {
        __syncthreads();
#pragma unroll
        for (int i = 0; i < 6; ++i) {
            int ch = tid + i * 256;
            int r = ch / 24, cc = ch - r * 24;
            *(short8*)&Ks[r * 200 + cc * 8] = kreg[i];
        }
        __syncthreads();
        if (lt + 4 <= tbi) {
            const unsigned short* kp = kbase + (long long)(lt + 4) * 64 * QK;
#pragma unroll
            for (int i = 0; i < 6; ++i) {
                int ch = tid + i * 256;
                int r = ch / 24, cc = ch - r * 24;
                kreg[i] = *(const short8*)(kp + r * QK + cc * 8);
            }
        }
        f32x4 d[4];
#pragma unroll
        for (int ls = 0; ls < 4; ++ls) d[ls] = (f32x4){0.f, 0.f, 0.f, 0.f};
#pragma unroll
        for (int f = 0; f < 6; ++f)
#pragma unroll
            for (int ls = 0; ls < 4; ++ls) {
                short8 bfr = *(const short8*)&Ks[(ls * 16 + c) * 200 + f * 32 + q * 8];
                d[ls] = MFMA16(af[f], bfr, d[ls]);
            }
        if (lt == tbi) {
#pragma unroll
            for (int ls = 0; ls < 4; ++ls)
#pragma unroll
                for (int r = 0; r < 4; ++r) {
                    int l = lt * 64 + ls * 16 + c;
                    int t = tw + q * 4 + r;
                    if (l <= t) z[r] += exp2f(d[ls][r] * SCL2E);
                }
        } else {
#pragma unroll
            for (int ls = 0; ls < 4; ++ls)
#pragma unroll
                for (int r = 0; r < 4; ++r)
                    z[r] += exp2f(d[ls][r] * SCL2E);
        }
    }
#pragma unroll
    for (int off = 1; off < 16; off <<= 1)
#pragma unroll
        for (int r = 0; r < 4; ++r)
            z[r] += __shfl_xor(z[r], off);
    if (c == 0) {
#pragma unroll
        for (int r = 0; r < 4; ++r)
            atomicAdd(&zrow[n * T + tw + q * 4 + r], z[r]);
    }
}

// ---------------- Pass B: out[l][n*128+e] += sum_t exp(s_tl) V'[t,e] ----------------
// grid (T/64, NH, 2); 256 thr. Longest first; register-prefetch dbuf; V pre-scaled by 1/z.
__global__ __launch_bounds__(256) void attn_pv(const unsigned short* __restrict__ kh,
                                               const unsigned short* __restrict__ qh,
                                               const unsigned short* __restrict__ vt,
                                               unsigned short* __restrict__ outp)
{
    int li = (int)blockIdx.x;                // li=0 (nt=32, longest) first
    int n = (int)blockIdx.y, chunk = (int)blockIdx.z;
    int lbase = li * 64;
    int tid = (int)threadIdx.x, wave = tid >> 6, lane = tid & 63;
    int q = lane >> 4, c = lane & 15;
    int lb = lbase + wave * 16;

    __shared__ unsigned short Qs[64 * 200];   // 25600 B
    __shared__ unsigned short Vs[128 * 72];   // 18432 B
    __shared__ unsigned short Ps[4][16 * 72]; //  9216 B

    const unsigned short* kp = kh + ((long long)(n * T + lb + c)) * QK;
    short8 kf[6];
#pragma unroll
    for (int f = 0; f < 6; ++f) kf[f] = *(const short8*)(kp + f * 32 + q * 8);

    f32x4 acc[8];
#pragma unroll
    for (int et = 0; et < 8; ++et) acc[et] = (f32x4){0.f, 0.f, 0.f, 0.f};

    int nt = 32 - li;
    const unsigned short* vbase = vt + (long long)n * DH * T;
    const unsigned short* qbase = qh + (long long)n * T * QK;

    short8 qreg[6], vreg[4];
    int ti = chunk;
    if (ti < nt) {
        int t0 = lbase + ti * 64;
        const unsigned short* qp = qbase + (long long)t0 * QK;
#pragma unroll
        for (int i = 0; i < 6; ++i) {
            int ch = tid + i * 256;
            int r = ch / 24, cc = ch - r * 24;
            qreg[i] = *(const short8*)(qp + r * QK + cc * 8);
        }
        const unsigned short* vp = vbase + t0;
#pragma unroll
        for (int i = 0; i < 4; ++i) {
            int ch = tid + i * 256;
            int r = ch >> 3, cc = ch & 7;
            vreg[i] = *(const short8*)(vp + (long long)r * T + cc * 8);
        }
    }
    for (; ti < nt; ti += 2) {
        __syncthreads();
#pragma unroll
        for (int i = 0; i < 6; ++i) {
            int ch = tid + i * 256;
            int r = ch / 24, cc = ch - r * 24;
            *(short8*)&Qs[r * 200 + cc * 8] = qreg[i];
        }
#pragma unroll
        for (int i = 0; i < 4; ++i) {
            int ch = tid + i * 256;
            int r = ch >> 3, cc = ch & 7;
            *(short8*)&Vs[r * 72 + cc * 8] = vreg[i];
        }
        __syncthreads();
        int t0 = lbase + ti * 64;
        if (ti + 2 < nt) {
            int t1 = lbase + (ti + 2) * 64;
            const unsigned short* qp = qbase + (long long)t1 * QK;
#pragma unroll
            for (int i = 0; i < 6; ++i) {
                int ch = tid + i * 256;
                int r = ch / 24, cc = ch - r * 24;
                qreg[i] = *(const short8*)(qp + r * QK + cc * 8);
            }
            const unsigned short* vp = vbase + t1;
#pragma unroll
            for (int i = 0; i < 4; ++i) {
                int ch = tid + i * 256;
                int r = ch >> 3, cc = ch & 7;
                vreg[i] = *(const short8*)(vp + (long long)r * T + cc * 8);
            }
        }
        f32x4 d[4];
#pragma unroll
        for (int ts = 0; ts < 4; ++ts) d[ts] = (f32x4){0.f, 0.f, 0.f, 0.f};
#pragma unroll
        for (int f = 0; f < 6; ++f)
#pragma unroll
            for (int ts = 0; ts < 4; ++ts) {
                short8 bq = *(const short8*)&Qs[(ts * 16 + c) * 200 + f * 32 + q * 8];
                d[ts] = MFMA16(kf[f], bq, d[ts]);
            }
        bool diag = (ti == 0);   // only chunk 0's first tile touches the diagonal
#pragma unroll
        for (int ts = 0; ts < 4; ++ts) {
            int t = t0 + ts * 16 + c;
#pragma unroll
            for (int r = 0; r < 4; ++r) {
                int l = lb + q * 4 + r;
                float p = exp2f(d[ts][r] * SCL2E);
                if (diag && t < l) p = 0.f;
                Ps[wave][(q * 4 + r) * 72 + ts * 16 + c] = f2b(p);
            }
        }
        // per-wave LDS RAW (same wave writes then reads Ps[wave]) -> no barrier
#pragma unroll
        for (int kt = 0; kt < 2; ++kt) {
            short8 pf = *(const short8*)&Ps[wave][c * 72 + kt * 32 + q * 8];
#pragma unroll
            for (int et = 0; et < 8; ++et) {
                short8 vf = *(const short8*)&Vs[(et * 16 + c) * 72 + kt * 32 + q * 8];
                acc[et] = MFMA16(pf, vf, acc[et]);
            }
        }
    }
    unsigned short* op = outp + (long long)chunk * T * D;
#pragma unroll
    for (int et = 0; et < 8; ++et)
#pragma unroll
        for (int r = 0; r < 4; ++r)
            op[(long long)(lb + q * 4 + r) * D + n * 128 + et * 16 + c] = f2b(acc[et][r]);
}

// attn2b = bf16(pva + pvb)
__global__ __launch_bounds__(256) void sum_cast(const unsigned short* __restrict__ a,
                                                const unsigned short* __restrict__ b,
                                                unsigned short* __restrict__ o)
{
    long long i = ((long long)blockIdx.x * 256 + threadIdx.x) * 8;
    short8 va = *(const short8*)(a + i);
    short8 vb = *(const short8*)(b + i);
    short8 vo;
#pragma unroll
    for (int j = 0; j < 8; ++j)
        vo[j] = (short)f2b(b2f((unsigned short)va[j]) + b2f((unsigned short)vb[j]));
    *(short8*)(o + i) = vo;
}

} // namespace

extern "C" void kernel_launch(void* const* d_in, const int* in_sizes, int n_in,
                              void* d_out, int out_size, void* d_ws, size_t ws_size,
                              hipStream_t stream)
{
    (void)in_sizes; (void)n_in; (void)out_size; (void)ws_size;
    const float* h    = (const float*)d_in[0];
    const float* fr   = (const float*)d_in[1];
    const float* wdkv = (const float*)d_in[3];
    const float* wuk  = (const float*)d_in[4];
    const float* wuv  = (const float*)d_in[5];
    const float* wdq  = (const float*)d_in[6];
    const float* wuq  = (const float*)d_in[7];
    const float* wqr  = (const float*)d_in[8];
    const float* wkr  = (const float*)d_in[9];
    const float* wo   = (const float*)d_in[10];
    float* out = (float*)d_out;

    char* p = (char*)d_ws;
    auto alloc = [&](long long bytes) { char* r = p; p += (bytes + 255) & ~255LL; return r; };
    unsigned short* hb    = (unsigned short*)alloc(SZ_H * 2);
    unsigned short* dkvb  = (unsigned short*)alloc(SZ_DKV * 2);
    unsigned short* ukb   = (unsigned short*)alloc(SZ_UK * 2);
    unsigned short* uvb   = (unsigned short*)alloc(SZ_UV * 2);
    unsigned short* dqb   = (unsigned short*)alloc(SZ_DQ * 2);
    unsigned short* uqb   = (unsigned short*)alloc(SZ_UQ * 2);
    unsigned short* qrb   = (unsigned short*)alloc(SZ_QR * 2);
    unsigned short* krb   = (unsigned short*)alloc(SZ_KR * 2);
    unsigned short* wob   = (unsigned short*)alloc((long long)D * D * 2);
    unsigned short* ckvb  = (unsigned short*)alloc((long long)T * DC * 2);
    unsigned short* cqb   = (unsigned short*)alloc((long long)T * DC * 2);
    float*          krt   = (float*)alloc((long long)T * DRH * 4);
    unsigned short* qhb   = (unsigned short*)alloc((long long)NH * T * QK * 2);
    unsigned short* khb   = (unsigned short*)alloc((long long)NH * T * QK * 2);
    unsigned short* vbh   = (unsigned short*)alloc((long long)NH * T * DH * 2);
    unsigned short* vtb   = (unsigned short*)alloc((long long)NH * T * DH * 2);
    float*          zrow  = (float*)alloc((long long)NH * T * 4);
    unsigned short* attn2 = (unsigned short*)alloc((long long)T * D * 2);
    // PV partial buffers (2 x T*D bf16 = 16 MB) overlay hb..dqb (dead by attn_pv time)
    unsigned short* pvp   = hb;

    cast_all<<<dim3((unsigned)(C7 / 1024)), 256, 0, stream>>>(
        h, wdkv, wuk, wuv, wdq, wuq, wqr, wkr, hb, dkvb, ukb, uvb, dqb, uqb, qrb, krb);
    wo_permute<<<dim3(D), 256, 0, stream>>>(wo, wob);

    gemm_bf16<128,128,64,64,true><<<dim3(T/128, DC/128, 1), 256, 0, stream>>>(
        hb, dkvb, ckvb, D, D, D, DC, 0, 0);
    gemm_bf16<128,128,64,64,true><<<dim3(T/128, DC/128, 1), 256, 0, stream>>>(
        hb, dqb, cqb, D, D, D, DC, 0, 0);
    gemm_bf16<128,64,32,64,false><<<dim3(T/128, 1, 1), 256, 0, stream>>>(
        hb, krb, krt, D, D, D, DRH, 0, 0);
    gemm_bf16<128,128,64,64,true><<<dim3(T/128, 1, NH), 256, 0, stream>>>(
        ckvb, ukb, khb, DC, DC, NH*DC, QK, DC, (long long)T * QK);
    gemm_bf16<128,128,64,64,true><<<dim3(T/128, 1, NH), 256, 0, stream>>>(
        ckvb, uvb, vbh, DC, DC, NH*DC, DH, DC, (long long)T * DH);
    gemm_bf16<128,128,64,64,true><<<dim3(T/128, 1, NH), 256, 0, stream>>>(
        cqb, uqb, qhb, DC, DC, NH*DC, QK, DC, (long long)T * QK);
    gemm_bf16<128,64,32,64,true><<<dim3(T/128, 1, NH), 256, 0, stream>>>(
        cqb, qrb, qhb + DH, DC, DC, NH*DC, QK, DC, (long long)T * QK);

    rope_q<<<dim3(NH * T * 32 / 256), 256, 0, stream>>>(qhb, fr);
    rope_k<<<dim3(T * 32 / 256), 256, 0, stream>>>(krt, khb, fr);

    hipMemsetAsync(zrow, 0, (long long)NH * T * 4, stream);
    row_stats<<<dim3(T/64, NH, 4), 256, 0, stream>>>(qhb, khb, zrow);
    vtrans<<<dim3(T/32, DH/32, NH), 256, 0, stream>>>(vbh, zrow, vtb);
    attn_pv<<<dim3(T/64, NH, 2), 256, 0, stream>>>(khb, qhb, vtb, pvp);
    sum_cast<<<dim3(T * D / 2048), 256, 0, stream>>>(pvp, pvp + (long long)T * D, attn2);

    gemm_bf16<128,128,64,64,false><<<dim3(T/128, D/128, 1), 256, 0, stream>>>(
        attn2, wob, out, D, D, D, D, 0, 0);
}